// Round 2
// baseline (572.505 us; speedup 1.0000x reference)
//
#include <hip/hip_runtime.h>

// Problem constants (from reference)
#define BQ 4
#define LQ 1536
#define KQ 30
#define NUM_RBF 16
#define NUM_POS 16
#define EDGE_F 128
#define EDGE_IN 167   // 16 + 16*9 + 7
#define POS_CLS 66    // 2*MAX_REL+2

// ---------- helpers ----------
__device__ __forceinline__ float ssq3_exact(float dx, float dy, float dz) {
    // ((dx*dx + dy*dy) + dz*dz), no FMA, sequential: numpy semantics
    return __fadd_rn(__fadd_rn(__fmul_rn(dx, dx), __fmul_rn(dy, dy)), __fmul_rn(dz, dz));
}

__device__ __forceinline__ float edist_exact(float ax, float ay, float az,
                                             float bx, float by, float bz) {
    float dx = __fsub_rn(ax, bx), dy = __fsub_rn(ay, by), dz = __fsub_rn(az, bz);
    return __fsqrt_rn(__fadd_rn(ssq3_exact(dx, dy, dz), 1e-6f));
}

__device__ __forceinline__ float sgnf(float x) {
    return (x > 0.f) ? 1.f : ((x < 0.f) ? -1.f : 0.f);
}

__device__ __forceinline__ unsigned long long umin64(unsigned long long a, unsigned long long b) {
    return a < b ? a : b;
}

// ---------- kernel A: per-node orientation frames O (B,L,9) ----------
__global__ __launch_bounds__(256) void kOnode(const float* __restrict__ Ca,
                                              float* __restrict__ Onode) {
    int idx = blockIdx.x * 256 + threadIdx.x;
    if (idx >= BQ * LQ) return;
    int b = idx / LQ, l = idx - b * LQ;
    float o[9];
#pragma unroll
    for (int r = 0; r < 9; ++r) o[r] = 0.f;
    if (l >= 1 && l <= LQ - 3) {
        const float* Xb = Ca + (size_t)b * LQ * 3;
        float xm = Xb[(l - 1) * 3 + 0], ym = Xb[(l - 1) * 3 + 1], zm = Xb[(l - 1) * 3 + 2];
        float x0 = Xb[l * 3 + 0],       y0 = Xb[l * 3 + 1],       z0 = Xb[l * 3 + 2];
        float xp = Xb[(l + 1) * 3 + 0], yp = Xb[(l + 1) * 3 + 1], zp = Xb[(l + 1) * 3 + 2];
        // u2 = U[l-1] from dX = X[l]-X[l-1]
        float ax = __fsub_rn(x0, xm), ay = __fsub_rn(y0, ym), az = __fsub_rn(z0, zm);
        float dna = __fsqrt_rn(__fadd_rn(ssq3_exact(ax, ay, az), 1e-12f));
        float ba = (dna > 3.6f && dna < 4.0f) ? 1.0f : 0.0f;
        float ux = ax * ba, uy = ay * ba, uz = az * ba;
        float rn = 1.0f / __fsqrt_rn(ux * ux + uy * uy + uz * uz + 1e-12f);
        ux *= rn; uy *= rn; uz *= rn;
        // u1 = U[l] from dX = X[l+1]-X[l]
        float bx = __fsub_rn(xp, x0), by = __fsub_rn(yp, y0), bz = __fsub_rn(zp, z0);
        float dnb = __fsqrt_rn(__fadd_rn(ssq3_exact(bx, by, bz), 1e-12f));
        float bb = (dnb > 3.6f && dnb < 4.0f) ? 1.0f : 0.0f;
        float vx = bx * bb, vy = by * bb, vz = bz * bb;
        rn = 1.0f / __fsqrt_rn(vx * vx + vy * vy + vz * vz + 1e-12f);
        vx *= rn; vy *= rn; vz *= rn;
        // o1 = norml(u2-u1)
        float ox = ux - vx, oy = uy - vy, oz = uz - vz;
        rn = 1.0f / __fsqrt_rn(ox * ox + oy * oy + oz * oz + 1e-12f);
        ox *= rn; oy *= rn; oz *= rn;
        // n2 = norml(cross(u2,u1))
        float cx = uy * vz - uz * vy, cy = uz * vx - ux * vz, cz = ux * vy - uy * vx;
        rn = 1.0f / __fsqrt_rn(cx * cx + cy * cy + cz * cz + 1e-12f);
        cx *= rn; cy *= rn; cz *= rn;
        // r3 = cross(o1,n2)  (NOT normalized in reference)
        float rx = oy * cz - oz * cy, ry = oz * cx - ox * cz, rz = ox * cy - oy * cx;
        o[0] = ox; o[1] = oy; o[2] = oz;
        o[3] = cx; o[4] = cy; o[5] = cz;
        o[6] = rx; o[7] = ry; o[8] = rz;
    }
    float* dst = Onode + (size_t)idx * 9;
#pragma unroll
    for (int r = 0; r < 9; ++r) dst[r] = o[r];
}

// ---------- kernel B: distances + top-K per row ----------
__global__ __launch_bounds__(256) void ktopk(const float* __restrict__ Ca,
                                             const float* __restrict__ mask,
                                             int* __restrict__ Eidx,
                                             float* __restrict__ Dn,
                                             float* __restrict__ outI) {
    const int row = blockIdx.x;
    const int b = row / LQ, i = row - b * LQ;
    const int tid = threadIdx.x;
    __shared__ float Drow[LQ];
    __shared__ unsigned long long keys[LQ];
    __shared__ unsigned long long redk[4];
    __shared__ unsigned long long swin;
    __shared__ float redf[4];
    __shared__ float sdmax;

    const float* Cb = Ca + (size_t)b * LQ * 3;
    const float* Mb = mask + (size_t)b * LQ;
    const float xi = Cb[i * 3 + 0], yi = Cb[i * 3 + 1], zi = Cb[i * 3 + 2];
    const float mi = Mb[i];

    float lmax = 0.0f;
    for (int j = tid; j < LQ; j += 256) {
        float dx = __fsub_rn(Cb[j * 3 + 0], xi);
        float dy = __fsub_rn(Cb[j * 3 + 1], yi);
        float dz = __fsub_rn(Cb[j * 3 + 2], zi);
        float m2 = __fmul_rn(mi, Mb[j]);
        float d = __fmul_rn(m2, __fsqrt_rn(__fadd_rn(ssq3_exact(dx, dy, dz), 1e-6f)));
        Drow[j] = d;
        lmax = fmaxf(lmax, d);
    }
    for (int off = 32; off; off >>= 1) lmax = fmaxf(lmax, __shfl_down(lmax, off));
    if ((tid & 63) == 0) redf[tid >> 6] = lmax;
    __syncthreads();
    if (tid == 0) sdmax = fmaxf(fmaxf(redf[0], redf[1]), fmaxf(redf[2], redf[3]));
    __syncthreads();
    const float Dmax = sdmax;
    for (int j = tid; j < LQ; j += 256) {
        float m2 = __fmul_rn(mi, Mb[j]);
        float adj = __fadd_rn(Drow[j], __fmul_rn(__fsub_rn(1.0f, m2), Dmax));
        keys[j] = (((unsigned long long)__float_as_uint(adj)) << 32) | (unsigned)j;
    }
    __syncthreads();

    for (int k = 0; k < KQ; ++k) {
        unsigned long long m = ~0ull;
#pragma unroll
        for (int s = 0; s < LQ / 256; ++s) m = umin64(m, keys[tid + s * 256]);
        for (int off = 32; off; off >>= 1) {
            unsigned long long o = __shfl_down(m, off);
            m = umin64(m, o);
        }
        if ((tid & 63) == 0) redk[tid >> 6] = m;
        __syncthreads();
        if (tid == 0) {
            m = umin64(umin64(redk[0], redk[1]), umin64(redk[2], redk[3]));
            swin = m;
            unsigned j = (unsigned)(m & 0xffffffffu);
            Eidx[(size_t)row * KQ + k] = (int)j;
            Dn[(size_t)row * KQ + k] = __uint_as_float((unsigned)(m >> 32));
            outI[(size_t)row * KQ + k] = (float)j;   // output dtype is float32
        }
        __syncthreads();
        unsigned jwin = (unsigned)(swin & 0xffffffffu);
        if ((jwin & 255u) == (unsigned)tid) keys[jwin] = ~0ull;
        __syncthreads();
    }
}

// ---------- kernel C: features + 167x128 GEMM + LayerNorm ----------
__global__ __launch_bounds__(256) void kfeat(const float* __restrict__ Ca,
                                             const int* __restrict__ ridx,
                                             const int* __restrict__ chl,
                                             const float* __restrict__ Wpos,
                                             const float* __restrict__ bpos,
                                             const float* __restrict__ Wedge,
                                             const float* __restrict__ gamma,
                                             const float* __restrict__ beta,
                                             const int* __restrict__ Eidx,
                                             const float* __restrict__ Dn,
                                             const float* __restrict__ Onode,
                                             float* __restrict__ outE) {
    const int row = blockIdx.x;
    const int b = row / LQ, i = row - b * LQ;
    const int tid = threadIdx.x;

    // EinT: transposed features [c][slot(e)], slot(e)=e+e/15 so each half owns 16 aligned lanes
    __shared__ __align__(16) float EinT[EDGE_IN + 1][32];
    __shared__ float Wt[128 * 43];
    __shared__ float Outb[KQ * 129];
    __shared__ float dists[KQ][9];
    __shared__ float smu[KQ], sinv[KQ];

    const float* Cb = Ca + (size_t)b * LQ * 3;

    // ---- phase 1: per-edge scalar features (threads 0..29) ----
    if (tid < KQ) {
        int e = tid;
        int j = Eidx[(size_t)row * KQ + e];
        int sl = e + e / 15;
        float pic[3] = {Cb[i * 3], Cb[i * 3 + 1], Cb[i * 3 + 2]};
        float pjc[3] = {Cb[j * 3], Cb[j * 3 + 1], Cb[j * 3 + 2]};
        float pi0[3] = {0.f, 0.f, 0.f}, pi2[3] = {0.f, 0.f, 0.f};
        float pj0[3] = {0.f, 0.f, 0.f}, pj2[3] = {0.f, 0.f, 0.f};
        if (i > 0)      { pi0[0] = Cb[(i - 1) * 3]; pi0[1] = Cb[(i - 1) * 3 + 1]; pi0[2] = Cb[(i - 1) * 3 + 2]; }
        if (i < LQ - 1) { pi2[0] = Cb[(i + 1) * 3]; pi2[1] = Cb[(i + 1) * 3 + 1]; pi2[2] = Cb[(i + 1) * 3 + 2]; }
        if (j > 0)      { pj0[0] = Cb[(j - 1) * 3]; pj0[1] = Cb[(j - 1) * 3 + 1]; pj0[2] = Cb[(j - 1) * 3 + 2]; }
        if (j < LQ - 1) { pj2[0] = Cb[(j + 1) * 3]; pj2[1] = Cb[(j + 1) * 3 + 1]; pj2[2] = Cb[(j + 1) * 3 + 2]; }

        dists[e][0] = Dn[(size_t)row * KQ + e];
        dists[e][1] = edist_exact(pi0[0], pi0[1], pi0[2], pj0[0], pj0[1], pj0[2]);
        dists[e][2] = edist_exact(pi2[0], pi2[1], pi2[2], pj2[0], pj2[1], pj2[2]);
        dists[e][3] = edist_exact(pi0[0], pi0[1], pi0[2], pjc[0], pjc[1], pjc[2]);
        dists[e][4] = edist_exact(pi0[0], pi0[1], pi0[2], pj2[0], pj2[1], pj2[2]);
        dists[e][5] = edist_exact(pic[0], pic[1], pic[2], pj0[0], pj0[1], pj0[2]);
        dists[e][6] = edist_exact(pic[0], pic[1], pic[2], pj2[0], pj2[1], pj2[2]);
        dists[e][7] = edist_exact(pi2[0], pi2[1], pi2[2], pj0[0], pj0[1], pj0[2]);
        dists[e][8] = edist_exact(pi2[0], pi2[1], pi2[2], pjc[0], pjc[1], pjc[2]);

        // positional features
        int off = ridx[(size_t)b * LQ + i] - ridx[(size_t)b * LQ + j];
        int ech = (chl[(size_t)b * LQ + i] == chl[(size_t)b * LQ + j]);
        int dd = ech ? min(max(off + 32, 0), 64) : 65;
#pragma unroll
        for (int f = 0; f < NUM_POS; ++f) EinT[f][sl] = Wpos[f * POS_CLS + dd] + bpos[f];

        // orientation features
        const float* Op = Onode + ((size_t)b * LQ + i) * 9;
        const float* Oq = Onode + ((size_t)b * LQ + j) * 9;
        float oi[9], oj[9];
#pragma unroll
        for (int r = 0; r < 9; ++r) { oi[r] = Op[r]; oj[r] = Oq[r]; }
        float dx = pjc[0] - pic[0], dy = pjc[1] - pic[1], dz = pjc[2] - pic[2];
        float v0 = oi[0] * dx + oi[1] * dy + oi[2] * dz;
        float v1 = oi[3] * dx + oi[4] * dy + oi[5] * dz;
        float v2 = oi[6] * dx + oi[7] * dy + oi[8] * dz;
        float rn = 1.0f / __fsqrt_rn(v0 * v0 + v1 * v1 + v2 * v2 + 1e-12f);
        EinT[160][sl] = v0 * rn;
        EinT[161][sl] = v1 * rn;
        EinT[162][sl] = v2 * rn;
        // R = Oi^T * Oj  -> R[ii][mm] = sum_j oi[3j+ii]*oj[3j+mm]
        float R[3][3];
#pragma unroll
        for (int ii = 0; ii < 3; ++ii)
#pragma unroll
            for (int mm = 0; mm < 3; ++mm)
                R[ii][mm] = oi[ii] * oj[mm] + oi[3 + ii] * oj[3 + mm] + oi[6 + ii] * oj[6 + mm];
        float Rxx = R[0][0], Ryy = R[1][1], Rzz = R[2][2];
        float m0 = 0.5f * __fsqrt_rn(fabsf(1.0f + (Rxx - Ryy - Rzz)) + 1e-12f);
        float m1 = 0.5f * __fsqrt_rn(fabsf(1.0f + (-Rxx + Ryy - Rzz)) + 1e-12f);
        float m2 = 0.5f * __fsqrt_rn(fabsf(1.0f + (-Rxx - Ryy + Rzz)) + 1e-12f);
        float qx = sgnf(R[2][1] - R[1][2]) * m0;
        float qy = sgnf(R[0][2] - R[2][0]) * m1;
        float qz = sgnf(R[1][0] - R[0][1]) * m2;
        float qw = __fsqrt_rn(fmaxf(1.0f + (Rxx + Ryy + Rzz), 0.0f) + 1e-12f) * 0.5f;
        rn = 1.0f / __fsqrt_rn(qx * qx + qy * qy + qz * qz + qw * qw + 1e-12f);
        EinT[163][sl] = qx * rn;
        EinT[164][sl] = qy * rn;
        EinT[165][sl] = qz * rn;
        EinT[166][sl] = qw * rn;
    }
    __syncthreads();

    // ---- phase 2: RBF features (30 edges x 144) ----
    for (int t = tid; t < KQ * 144; t += 256) {
        int e = t / 144;
        int c = t - e * 144;
        int s = c >> 4, r = c & 15;
        float mu = 2.0f + (float)r * (20.0f / 15.0f);
        float z = (dists[e][s] - mu) / 1.25f;
        EinT[NUM_POS + c][e + e / 15] = expf(-(z * z));
    }
    __syncthreads();

    // ---- phase 3: GEMM  out[e][f] = sum_c Ein[e][c] * Wedge[f][c] ----
    float acc[15];
#pragma unroll
    for (int e2 = 0; e2 < 15; ++e2) acc[e2] = 0.f;
    const int f = tid & 127;
    const int h = tid >> 7;   // half: edges [h*15, h*15+15)
    for (int c0 = 0; c0 < EDGE_IN; c0 += 43) {
        int cn = min(43, EDGE_IN - c0);
        for (int t = tid; t < 128 * cn; t += 256) {
            int ff = t / cn, cc = t - ff * cn;
            Wt[ff * 43 + cc] = Wedge[(size_t)ff * EDGE_IN + c0 + cc];
        }
        __syncthreads();
        for (int cc = 0; cc < cn; ++cc) {
            float w = Wt[f * 43 + cc];
            const float* rp = &EinT[c0 + cc][h * 16];
            float4 a0 = *(const float4*)(rp);
            float4 a1 = *(const float4*)(rp + 4);
            float4 a2 = *(const float4*)(rp + 8);
            float4 a3 = *(const float4*)(rp + 12);
            acc[0]  = fmaf(a0.x, w, acc[0]);
            acc[1]  = fmaf(a0.y, w, acc[1]);
            acc[2]  = fmaf(a0.z, w, acc[2]);
            acc[3]  = fmaf(a0.w, w, acc[3]);
            acc[4]  = fmaf(a1.x, w, acc[4]);
            acc[5]  = fmaf(a1.y, w, acc[5]);
            acc[6]  = fmaf(a1.z, w, acc[6]);
            acc[7]  = fmaf(a1.w, w, acc[7]);
            acc[8]  = fmaf(a2.x, w, acc[8]);
            acc[9]  = fmaf(a2.y, w, acc[9]);
            acc[10] = fmaf(a2.z, w, acc[10]);
            acc[11] = fmaf(a2.w, w, acc[11]);
            acc[12] = fmaf(a3.x, w, acc[12]);
            acc[13] = fmaf(a3.y, w, acc[13]);
            acc[14] = fmaf(a3.z, w, acc[14]);
            // a3.w = slot 15/31, unused pad
        }
        __syncthreads();
    }
#pragma unroll
    for (int e2 = 0; e2 < 15; ++e2) Outb[(h * 15 + e2) * 129 + f] = acc[e2];
    __syncthreads();

    // ---- phase 4: LayerNorm stats ----
    if (tid < KQ) {
        int e = tid;
        float s = 0.f;
        for (int f2 = 0; f2 < EDGE_F; ++f2) s += Outb[e * 129 + f2];
        float mu = s / (float)EDGE_F;
        float s2 = 0.f;
        for (int f2 = 0; f2 < EDGE_F; ++f2) {
            float d = Outb[e * 129 + f2] - mu;
            s2 += d * d;
        }
        float var = s2 / (float)EDGE_F;
        smu[e] = mu;
        sinv[e] = 1.0f / __fsqrt_rn(var + 1e-5f);
    }
    __syncthreads();

    // ---- phase 5: normalize + f32 store (coalesced) ----
    float* dst = outE + (size_t)row * (KQ * EDGE_F);
    for (int t = tid; t < KQ * EDGE_F; t += 256) {
        int e = t >> 7, f2 = t & 127;
        float val = (Outb[e * 129 + f2] - smu[e]) * sinv[e] * gamma[f2] + beta[f2];
        dst[t] = val;
    }
}

extern "C" void kernel_launch(void* const* d_in, const int* in_sizes, int n_in,
                              void* d_out, int out_size, void* d_ws, size_t ws_size,
                              hipStream_t stream) {
    const float* Ca    = (const float*)d_in[0];
    const float* mask  = (const float*)d_in[1];
    const int*   ridx  = (const int*)d_in[2];
    const int*   chl   = (const int*)d_in[3];
    const float* Wpos  = (const float*)d_in[4];
    const float* bpos  = (const float*)d_in[5];
    const float* Wedge = (const float*)d_in[6];
    const float* gamma = (const float*)d_in[7];
    const float* beta  = (const float*)d_in[8];

    float* outE = (float*)d_out;                                        // E: B*L*K*128 f32
    float* outI = outE + (size_t)BQ * LQ * KQ * EDGE_F;                 // E_idx: B*L*K (as f32)

    char* ws = (char*)d_ws;
    int*   Eidx  = (int*)(ws + 0);                                      // B*L*K ints
    float* Dn    = (float*)(ws + (size_t)BQ * LQ * KQ * 4);             // B*L*K floats
    float* Onode = (float*)(ws + (size_t)BQ * LQ * KQ * 8);             // B*L*9 floats

    kOnode<<<(BQ * LQ + 255) / 256, 256, 0, stream>>>(Ca, Onode);
    ktopk<<<BQ * LQ, 256, 0, stream>>>(Ca, mask, Eidx, Dn, outI);
    kfeat<<<BQ * LQ, 256, 0, stream>>>(Ca, ridx, chl, Wpos, bpos, Wedge, gamma, beta,
                                       Eidx, Dn, Onode, outE);
}

// Round 5
// 230.156 us; speedup vs baseline: 2.4875x; 2.4875x over previous
//
#include <hip/hip_runtime.h>

// Problem constants (from reference)
#define BQ 4
#define LQ 1536
#define KQ 30
#define NUM_RBF 16
#define NUM_POS 16
#define EDGE_F 128
#define EDGE_IN 167   // 16 + 16*9 + 7
#define KPAD 192      // EDGE_IN padded to 6 K-tiles of 32
#define POS_CLS 66    // 2*MAX_REL+2

typedef __attribute__((ext_vector_type(8))) short bf16x8;
typedef __attribute__((ext_vector_type(4))) float f32x4;

// ---------- helpers ----------
__device__ __forceinline__ float ssq3_exact(float dx, float dy, float dz) {
    return __fadd_rn(__fadd_rn(__fmul_rn(dx, dx), __fmul_rn(dy, dy)), __fmul_rn(dz, dz));
}

__device__ __forceinline__ float edist_exact(float ax, float ay, float az,
                                             float bx, float by, float bz) {
    float dx = __fsub_rn(ax, bx), dy = __fsub_rn(ay, by), dz = __fsub_rn(az, bz);
    return __fsqrt_rn(__fadd_rn(ssq3_exact(dx, dy, dz), 1e-6f));
}

__device__ __forceinline__ unsigned short f2bf(float x) {
    unsigned int u = __float_as_uint(x);
    unsigned int r = (u + 0x7fffu + ((u >> 16) & 1u)) >> 16;   // RTNE
    return (unsigned short)r;
}

__device__ __forceinline__ float sgnf(float x) {
    return (x > 0.f) ? 1.f : ((x < 0.f) ? -1.f : 0.f);
}

__device__ __forceinline__ unsigned long long umin64(unsigned long long a, unsigned long long b) {
    return a < b ? a : b;
}

// fragment-order offset for A (Ein): element index within A_frag for (edge e, col c)
__device__ __forceinline__ int fragoff(int e, int c) {
    int m = e >> 4, kk = c >> 5;
    int l = (e & 15) | (((c >> 3) & 3) << 4);
    return (((m * 6 + kk) * 64 + l) << 3) | (c & 7);
}

// ---------- kernel W-pack: Wedge[f][c] -> bf16 fragments wpack[kk][n][lane][j] ----------
__global__ __launch_bounds__(256) void kWpack(const float* __restrict__ Wedge,
                                              unsigned short* __restrict__ wpack) {
    int idx = blockIdx.x * 256 + threadIdx.x;   // 6*8*64*8 = 24576
    if (idx >= 6 * 8 * 64 * 8) return;
    int j = idx & 7, l = (idx >> 3) & 63, n = (idx >> 9) & 7, kk = idx >> 12;
    int c = kk * 32 + ((l >> 4) << 3) + j;
    int f = (n << 4) + (l & 15);
    float v = (c < EDGE_IN) ? Wedge[(size_t)f * EDGE_IN + c] : 0.0f;
    wpack[idx] = f2bf(v);
}

// ---------- kernel A: per-node orientation frames O (B,L,9) ----------
__global__ __launch_bounds__(256) void kOnode(const float* __restrict__ Ca,
                                              float* __restrict__ Onode) {
    int idx = blockIdx.x * 256 + threadIdx.x;
    if (idx >= BQ * LQ) return;
    int b = idx / LQ, l = idx - b * LQ;
    float o[9];
#pragma unroll
    for (int r = 0; r < 9; ++r) o[r] = 0.f;
    if (l >= 1 && l <= LQ - 3) {
        const float* Xb = Ca + (size_t)b * LQ * 3;
        float xm = Xb[(l - 1) * 3 + 0], ym = Xb[(l - 1) * 3 + 1], zm = Xb[(l - 1) * 3 + 2];
        float x0 = Xb[l * 3 + 0],       y0 = Xb[l * 3 + 1],       z0 = Xb[l * 3 + 2];
        float xp = Xb[(l + 1) * 3 + 0], yp = Xb[(l + 1) * 3 + 1], zp = Xb[(l + 1) * 3 + 2];
        float ax = __fsub_rn(x0, xm), ay = __fsub_rn(y0, ym), az = __fsub_rn(z0, zm);
        float dna = __fsqrt_rn(__fadd_rn(ssq3_exact(ax, ay, az), 1e-12f));
        float ba = (dna > 3.6f && dna < 4.0f) ? 1.0f : 0.0f;
        float ux = ax * ba, uy = ay * ba, uz = az * ba;
        float rn = 1.0f / __fsqrt_rn(ux * ux + uy * uy + uz * uz + 1e-12f);
        ux *= rn; uy *= rn; uz *= rn;
        float bx = __fsub_rn(xp, x0), by = __fsub_rn(yp, y0), bz = __fsub_rn(zp, z0);
        float dnb = __fsqrt_rn(__fadd_rn(ssq3_exact(bx, by, bz), 1e-12f));
        float bb = (dnb > 3.6f && dnb < 4.0f) ? 1.0f : 0.0f;
        float vx = bx * bb, vy = by * bb, vz = bz * bb;
        rn = 1.0f / __fsqrt_rn(vx * vx + vy * vy + vz * vz + 1e-12f);
        vx *= rn; vy *= rn; vz *= rn;
        float ox = ux - vx, oy = uy - vy, oz = uz - vz;
        rn = 1.0f / __fsqrt_rn(ox * ox + oy * oy + oz * oz + 1e-12f);
        ox *= rn; oy *= rn; oz *= rn;
        float cx = uy * vz - uz * vy, cy = uz * vx - ux * vz, cz = ux * vy - uy * vx;
        rn = 1.0f / __fsqrt_rn(cx * cx + cy * cy + cz * cz + 1e-12f);
        cx *= rn; cy *= rn; cz *= rn;
        float rx = oy * cz - oz * cy, ry = oz * cx - ox * cz, rz = ox * cy - oy * cx;
        o[0] = ox; o[1] = oy; o[2] = oz;
        o[3] = cx; o[4] = cy; o[5] = cz;
        o[6] = rx; o[7] = ry; o[8] = rz;
    }
    float* dst = Onode + (size_t)idx * 9;
#pragma unroll
    for (int r = 0; r < 9; ++r) dst[r] = o[r];
}

// ---------- kernel B: top-K, one wave per row, keys in registers ----------
__global__ __launch_bounds__(64) void ktopk(const float* __restrict__ Ca,
                                            const float* __restrict__ mask,
                                            int* __restrict__ Eidx,
                                            float* __restrict__ Dn,
                                            float* __restrict__ outI) {
    const int row = blockIdx.x;
    const int b = row / LQ, i = row - b * LQ;
    const int lane = threadIdx.x;

    const float* Cb = Ca + (size_t)b * LQ * 3;
    const float* Mb = mask + (size_t)b * LQ;
    const float xi = Cb[i * 3 + 0], yi = Cb[i * 3 + 1], zi = Cb[i * 3 + 2];
    const float mi = Mb[i];

    float dv[24], m2v[24];
    float lmax = 0.0f;
#pragma unroll
    for (int s = 0; s < 24; ++s) {
        int j = lane + (s << 6);
        float dx = __fsub_rn(Cb[j * 3 + 0], xi);
        float dy = __fsub_rn(Cb[j * 3 + 1], yi);
        float dz = __fsub_rn(Cb[j * 3 + 2], zi);
        float m2 = __fmul_rn(mi, Mb[j]);
        float d = __fmul_rn(m2, __fsqrt_rn(__fadd_rn(ssq3_exact(dx, dy, dz), 1e-6f)));
        dv[s] = d; m2v[s] = m2;
        lmax = fmaxf(lmax, d);
    }
#pragma unroll
    for (int off = 1; off < 64; off <<= 1) lmax = fmaxf(lmax, __shfl_xor(lmax, off));
    const float Dmax = lmax;

    unsigned long long key[24];
#pragma unroll
    for (int s = 0; s < 24; ++s) {
        float adj = __fadd_rn(dv[s], __fmul_rn(__fsub_rn(1.0f, m2v[s]), Dmax));
        key[s] = (((unsigned long long)__float_as_uint(adj)) << 32) | (unsigned)(lane + (s << 6));
    }

    // local min + argmin
    unsigned long long lm = ~0ull; int li = 0;
#pragma unroll
    for (int s = 0; s < 24; ++s) { if (key[s] < lm) { lm = key[s]; li = s; } }

    unsigned int rm = 0;                 // removed mask
    unsigned long long res = 0;
#pragma unroll 1
    for (int k = 0; k < KQ; ++k) {
        unsigned long long g = lm;
#pragma unroll
        for (int off = 1; off < 64; off <<= 1) {
            unsigned long long o = __shfl_xor(g, off);
            g = umin64(g, o);
        }
        if (lane == k) res = g;
        if (lm == g) {   // unique winner pops and rescans
            rm |= (1u << li);
            lm = ~0ull; li = 0;
#pragma unroll
            for (int s = 0; s < 24; ++s) {
                if (!((rm >> s) & 1u) && key[s] < lm) { lm = key[s]; li = s; }
            }
        }
    }

    if (lane < KQ) {
        unsigned j = (unsigned)(res & 0xffffffffu);
        Eidx[(size_t)row * KQ + lane] = (int)j;
        Dn[(size_t)row * KQ + lane] = __uint_as_float((unsigned)(res >> 32));
        outI[(size_t)row * KQ + lane] = (float)j;
    }
}

// ---------- kernel C: features (bf16) + MFMA GEMM + LayerNorm ----------
__global__ __launch_bounds__(256) void kfeat(const float* __restrict__ Ca,
                                             const int* __restrict__ ridx,
                                             const int* __restrict__ chl,
                                             const float* __restrict__ Wpos,
                                             const float* __restrict__ bpos,
                                             const float* __restrict__ gamma,
                                             const float* __restrict__ beta,
                                             const int* __restrict__ Eidx,
                                             const float* __restrict__ Dn,
                                             const float* __restrict__ Onode,
                                             const unsigned short* __restrict__ wpack,
                                             float* __restrict__ outE) {
    const int row = blockIdx.x;
    const int b = row / LQ, i = row - b * LQ;
    const int tid = threadIdx.x;

    __shared__ __align__(16) unsigned short Afrag[2 * 6 * 64 * 8];   // 6144 u16 = 12288 B
    __shared__ __align__(16) float Outb[KQ * 132];                   // 15840 B
    __shared__ float dists[KQ][9];
    __shared__ int sEidx[KQ];
    __shared__ float sDn[KQ];

    const float* Cb = Ca + (size_t)b * LQ * 3;

    // ---- phase 0: zero ALL of Afrag (6144 u16 = 768 uint4 — r4 NaN bug was t<384), load Eidx/Dn ----
    {
        uint4* az = (uint4*)Afrag;
        for (int t = tid; t < 768; t += 256) az[t] = make_uint4(0, 0, 0, 0);
        if (tid < KQ) {
            sEidx[tid] = Eidx[(size_t)row * KQ + tid];
            sDn[tid] = Dn[(size_t)row * KQ + tid];
        }
    }
    __syncthreads();

    unsigned int* Apair = (unsigned int*)Afrag;   // dword view for pair writes

    // ---- phase 1: dists (u<270), orientation (270..299), positional (300..539) ----
    for (int u = tid; u < 540; u += 256) {
        if (u < 270) {
            int e = u / 9, s = u - e * 9;
            if (s == 0) {
                dists[e][0] = sDn[e];
            } else {
                const int TA[9] = {0, -1, 1, -1, -1, 0, 0, 1, 1};
                const int TB[9] = {0, -1, 1,  0,  1, -1, 1, -1, 0};
                int j = sEidx[e];
                int ia = i + TA[s], jb = j + TB[s];
                float ax = 0.f, ay = 0.f, az = 0.f, bx = 0.f, by = 0.f, bz = 0.f;
                if (ia >= 0 && ia < LQ) { ax = Cb[ia * 3]; ay = Cb[ia * 3 + 1]; az = Cb[ia * 3 + 2]; }
                if (jb >= 0 && jb < LQ) { bx = Cb[jb * 3]; by = Cb[jb * 3 + 1]; bz = Cb[jb * 3 + 2]; }
                dists[e][s] = edist_exact(ax, ay, az, bx, by, bz);
            }
        } else if (u < 300) {
            int e = u - 270;
            int j = sEidx[e];
            float pic0 = Cb[i * 3], pic1 = Cb[i * 3 + 1], pic2 = Cb[i * 3 + 2];
            float pjc0 = Cb[j * 3], pjc1 = Cb[j * 3 + 1], pjc2 = Cb[j * 3 + 2];
            const float* Op = Onode + ((size_t)b * LQ + i) * 9;
            const float* Oq = Onode + ((size_t)b * LQ + j) * 9;
            float oi[9], oj[9];
#pragma unroll
            for (int r = 0; r < 9; ++r) { oi[r] = Op[r]; oj[r] = Oq[r]; }
            float dx = pjc0 - pic0, dy = pjc1 - pic1, dz = pjc2 - pic2;
            float v0 = oi[0] * dx + oi[1] * dy + oi[2] * dz;
            float v1 = oi[3] * dx + oi[4] * dy + oi[5] * dz;
            float v2 = oi[6] * dx + oi[7] * dy + oi[8] * dz;
            float rn = 1.0f / __fsqrt_rn(v0 * v0 + v1 * v1 + v2 * v2 + 1e-12f);
            v0 *= rn; v1 *= rn; v2 *= rn;
            float R[3][3];
#pragma unroll
            for (int ii = 0; ii < 3; ++ii)
#pragma unroll
                for (int mm = 0; mm < 3; ++mm)
                    R[ii][mm] = oi[ii] * oj[mm] + oi[3 + ii] * oj[3 + mm] + oi[6 + ii] * oj[6 + mm];
            float Rxx = R[0][0], Ryy = R[1][1], Rzz = R[2][2];
            float m0 = 0.5f * __fsqrt_rn(fabsf(1.0f + (Rxx - Ryy - Rzz)) + 1e-12f);
            float m1 = 0.5f * __fsqrt_rn(fabsf(1.0f + (-Rxx + Ryy - Rzz)) + 1e-12f);
            float m2 = 0.5f * __fsqrt_rn(fabsf(1.0f + (-Rxx - Ryy + Rzz)) + 1e-12f);
            float qx = sgnf(R[2][1] - R[1][2]) * m0;
            float qy = sgnf(R[0][2] - R[2][0]) * m1;
            float qz = sgnf(R[1][0] - R[0][1]) * m2;
            float qw = __fsqrt_rn(fmaxf(1.0f + (Rxx + Ryy + Rzz), 0.0f) + 1e-12f) * 0.5f;
            rn = 1.0f / __fsqrt_rn(qx * qx + qy * qy + qz * qz + qw * qw + 1e-12f);
            qx *= rn; qy *= rn; qz *= rn; qw *= rn;
            // write pairs: c=160..166 (+ zero pad at 167)
            unsigned int p0 = (unsigned)f2bf(v0) | ((unsigned)f2bf(v1) << 16);
            unsigned int p1 = (unsigned)f2bf(v2) | ((unsigned)f2bf(qx) << 16);
            unsigned int p2 = (unsigned)f2bf(qy) | ((unsigned)f2bf(qz) << 16);
            unsigned int p3 = (unsigned)f2bf(qw);
            Apair[fragoff(e, 160) >> 1] = p0;
            Apair[fragoff(e, 162) >> 1] = p1;
            Apair[fragoff(e, 164) >> 1] = p2;
            Apair[fragoff(e, 166) >> 1] = p3;
        } else {
            int p = u - 300;                 // 240 jobs: e(30) x 8 pairs
            int e = p >> 3, pr = p & 7;
            int c = pr << 1;                 // 0..14
            int j = sEidx[e];
            int off = ridx[(size_t)b * LQ + i] - ridx[(size_t)b * LQ + j];
            int ech = (chl[(size_t)b * LQ + i] == chl[(size_t)b * LQ + j]);
            int dd = ech ? min(max(off + 32, 0), 64) : 65;
            float f0 = Wpos[c * POS_CLS + dd] + bpos[c];
            float f1 = Wpos[(c + 1) * POS_CLS + dd] + bpos[c + 1];
            Apair[fragoff(e, c) >> 1] = (unsigned)f2bf(f0) | ((unsigned)f2bf(f1) << 16);
        }
    }
    __syncthreads();

    // ---- phase 2: RBF features, written as bf16 pairs (30 x 72 pairs) ----
    for (int t = tid; t < KQ * 72; t += 256) {
        int e = t / 72, p = t - e * 72;
        int c = 16 + (p << 1);
        int s = (c - 16) >> 4, r = (c - 16) & 15;
        float d = dists[e][s];
        float z0 = (d - (2.0f + (float)r * 1.3333334f)) * 0.8f;
        float z1 = (d - (2.0f + (float)(r + 1) * 1.3333334f)) * 0.8f;
        float g0 = __expf(-(z0 * z0));
        float g1 = __expf(-(z1 * z1));
        Apair[fragoff(e, c) >> 1] = (unsigned)f2bf(g0) | ((unsigned)f2bf(g1) << 16);
    }
    __syncthreads();

    // ---- phase 3: MFMA GEMM: D[30x128] = A[32x192] * B[192x128] ----
    {
        const int l = tid & 63, w = tid >> 6;    // wave w owns f in [32w, 32w+32)
        const bf16x8* Af = (const bf16x8*)Afrag;
        const bf16x8* Bf = (const bf16x8*)wpack;
        f32x4 acc00 = {0.f, 0.f, 0.f, 0.f}, acc01 = acc00, acc10 = acc00, acc11 = acc00;
#pragma unroll
        for (int kk = 0; kk < 6; ++kk) {
            bf16x8 a0 = Af[kk * 64 + l];
            bf16x8 a1 = Af[(6 + kk) * 64 + l];
            bf16x8 b0 = Bf[(size_t)(kk * 8 + 2 * w) * 64 + l];
            bf16x8 b1 = Bf[(size_t)(kk * 8 + 2 * w + 1) * 64 + l];
            acc00 = __builtin_amdgcn_mfma_f32_16x16x32_bf16(a0, b0, acc00, 0, 0, 0);
            acc01 = __builtin_amdgcn_mfma_f32_16x16x32_bf16(a0, b1, acc01, 0, 0, 0);
            acc10 = __builtin_amdgcn_mfma_f32_16x16x32_bf16(a1, b0, acc10, 0, 0, 0);
            acc11 = __builtin_amdgcn_mfma_f32_16x16x32_bf16(a1, b1, acc11, 0, 0, 0);
        }
        // D layout: col = l&15, row = (l>>4)*4 + reg
        int colbase0 = (2 * w) * 16 + (l & 15);
        int colbase1 = (2 * w + 1) * 16 + (l & 15);
        int rbase = (l >> 4) * 4;
#pragma unroll
        for (int r = 0; r < 4; ++r) {
            int e0 = rbase + r;          // m=0 tile: rows 0..15 all valid
            Outb[e0 * 132 + colbase0] = acc00[r];
            Outb[e0 * 132 + colbase1] = acc01[r];
            int e1 = 16 + rbase + r;     // m=1 tile: rows 16..31, keep <30
            if (e1 < KQ) {
                Outb[e1 * 132 + colbase0] = acc10[r];
                Outb[e1 * 132 + colbase1] = acc11[r];
            }
        }
    }
    __syncthreads();

    // ---- phase 4: LayerNorm stats (8 threads per edge) ----
    __shared__ float smu[KQ], sinv[KQ];
    if (tid < KQ * 8) {
        int e = tid >> 3, g = tid & 7;
        float s1 = 0.f, s2 = 0.f;
#pragma unroll
        for (int q = 0; q < 16; ++q) {
            float v = Outb[e * 132 + g * 16 + q];
            s1 += v; s2 += v * v;
        }
#pragma unroll
        for (int off = 1; off < 8; off <<= 1) {
            s1 += __shfl_xor(s1, off);
            s2 += __shfl_xor(s2, off);
        }
        if (g == 0) {
            float mu = s1 * (1.0f / 128.0f);
            float var = s2 * (1.0f / 128.0f) - mu * mu;
            smu[e] = mu;
            sinv[e] = 1.0f / __fsqrt_rn(var + 1e-5f);
        }
    }
    __syncthreads();

    // ---- phase 5: normalize + f32 store (float4, coalesced) ----
    float* dst = outE + (size_t)row * (KQ * EDGE_F);
    for (int t = tid; t < KQ * EDGE_F / 4; t += 256) {
        int fi = t << 2;
        int e = fi >> 7, f0 = fi & 127;
        float4 x = *(const float4*)&Outb[e * 132 + f0];
        float4 gm = *(const float4*)&gamma[f0];
        float4 bt = *(const float4*)&beta[f0];
        float mu = smu[e], iv = sinv[e];
        float4 o;
        o.x = (x.x - mu) * iv * gm.x + bt.x;
        o.y = (x.y - mu) * iv * gm.y + bt.y;
        o.z = (x.z - mu) * iv * gm.z + bt.z;
        o.w = (x.w - mu) * iv * gm.w + bt.w;
        *(float4*)&dst[fi] = o;
    }
}

extern "C" void kernel_launch(void* const* d_in, const int* in_sizes, int n_in,
                              void* d_out, int out_size, void* d_ws, size_t ws_size,
                              hipStream_t stream) {
    const float* Ca    = (const float*)d_in[0];
    const float* mask  = (const float*)d_in[1];
    const int*   ridx  = (const int*)d_in[2];
    const int*   chl   = (const int*)d_in[3];
    const float* Wpos  = (const float*)d_in[4];
    const float* bpos  = (const float*)d_in[5];
    const float* Wedge = (const float*)d_in[6];
    const float* gamma = (const float*)d_in[7];
    const float* beta  = (const float*)d_in[8];

    float* outE = (float*)d_out;                                        // E: B*L*K*128 f32
    float* outI = outE + (size_t)BQ * LQ * KQ * EDGE_F;                 // E_idx: B*L*K (as f32)

    char* ws = (char*)d_ws;
    int*            Eidx  = (int*)(ws + 0);                                          // 737280 B
    float*          Dn    = (float*)(ws + (size_t)BQ * LQ * KQ * 4);                 // 737280 B
    float*          Onode = (float*)(ws + (size_t)BQ * LQ * KQ * 8);                 // 221184 B
    unsigned short* wpack = (unsigned short*)(ws + (size_t)BQ * LQ * KQ * 8 + (size_t)BQ * LQ * 9 * 4);  // 49152 B

    kWpack<<<96, 256, 0, stream>>>(Wedge, wpack);
    kOnode<<<(BQ * LQ + 255) / 256, 256, 0, stream>>>(Ca, Onode);
    ktopk<<<BQ * LQ, 64, 0, stream>>>(Ca, mask, Eidx, Dn, outI);
    kfeat<<<BQ * LQ, 256, 0, stream>>>(Ca, ridx, chl, Wpos, bpos, gamma, beta,
                                       Eidx, Dn, Onode, wpack, outE);
}

// Round 6
// 221.678 us; speedup vs baseline: 2.5826x; 1.0382x over previous
//
#include <hip/hip_runtime.h>

// Problem constants (from reference)
#define BQ 4
#define LQ 1536
#define KQ 30
#define NUM_RBF 16
#define NUM_POS 16
#define EDGE_F 128
#define EDGE_IN 167   // 16 + 16*9 + 7
#define KPAD 192      // EDGE_IN padded to 6 K-tiles of 32
#define POS_CLS 66    // 2*MAX_REL+2

typedef __attribute__((ext_vector_type(8))) short bf16x8;
typedef __attribute__((ext_vector_type(4))) float f32x4;

// ---------- helpers ----------
__device__ __forceinline__ float ssq3_exact(float dx, float dy, float dz) {
    return __fadd_rn(__fadd_rn(__fmul_rn(dx, dx), __fmul_rn(dy, dy)), __fmul_rn(dz, dz));
}

__device__ __forceinline__ float edist_exact(float ax, float ay, float az,
                                             float bx, float by, float bz) {
    float dx = __fsub_rn(ax, bx), dy = __fsub_rn(ay, by), dz = __fsub_rn(az, bz);
    return __fsqrt_rn(__fadd_rn(ssq3_exact(dx, dy, dz), 1e-6f));
}

__device__ __forceinline__ unsigned short f2bf(float x) {
    unsigned int u = __float_as_uint(x);
    unsigned int r = (u + 0x7fffu + ((u >> 16) & 1u)) >> 16;   // RTNE
    return (unsigned short)r;
}

__device__ __forceinline__ float sgnf(float x) {
    return (x > 0.f) ? 1.f : ((x < 0.f) ? -1.f : 0.f);
}

__device__ __forceinline__ unsigned long long umin64(unsigned long long a, unsigned long long b) {
    return a < b ? a : b;
}

// fragment-order offset for A (Ein): element index within A_frag for (edge e, col c)
__device__ __forceinline__ int fragoff(int e, int c) {
    int m = e >> 4, kk = c >> 5;
    int l = (e & 15) | (((c >> 3) & 3) << 4);
    return (((m * 6 + kk) * 64 + l) << 3) | (c & 7);
}

// ---------- kernel prep: fused kWpack (blocks 0..95) + kOnode (blocks 96..119) ----------
__global__ __launch_bounds__(256) void kprep(const float* __restrict__ Wedge,
                                             unsigned short* __restrict__ wpack,
                                             const float* __restrict__ Ca,
                                             float* __restrict__ Onode) {
    if (blockIdx.x < 96) {
        int idx = blockIdx.x * 256 + threadIdx.x;   // 6*8*64*8 = 24576
        if (idx >= 6 * 8 * 64 * 8) return;
        int j = idx & 7, l = (idx >> 3) & 63, n = (idx >> 9) & 7, kk = idx >> 12;
        int c = kk * 32 + ((l >> 4) << 3) + j;
        int f = (n << 4) + (l & 15);
        float v = (c < EDGE_IN) ? Wedge[(size_t)f * EDGE_IN + c] : 0.0f;
        wpack[idx] = f2bf(v);
        return;
    }
    int idx = (blockIdx.x - 96) * 256 + threadIdx.x;
    if (idx >= BQ * LQ) return;
    int b = idx / LQ, l = idx - b * LQ;
    float o[9];
#pragma unroll
    for (int r = 0; r < 9; ++r) o[r] = 0.f;
    if (l >= 1 && l <= LQ - 3) {
        const float* Xb = Ca + (size_t)b * LQ * 3;
        float xm = Xb[(l - 1) * 3 + 0], ym = Xb[(l - 1) * 3 + 1], zm = Xb[(l - 1) * 3 + 2];
        float x0 = Xb[l * 3 + 0],       y0 = Xb[l * 3 + 1],       z0 = Xb[l * 3 + 2];
        float xp = Xb[(l + 1) * 3 + 0], yp = Xb[(l + 1) * 3 + 1], zp = Xb[(l + 1) * 3 + 2];
        float ax = __fsub_rn(x0, xm), ay = __fsub_rn(y0, ym), az = __fsub_rn(z0, zm);
        float dna = __fsqrt_rn(__fadd_rn(ssq3_exact(ax, ay, az), 1e-12f));
        float ba = (dna > 3.6f && dna < 4.0f) ? 1.0f : 0.0f;
        float ux = ax * ba, uy = ay * ba, uz = az * ba;
        float rn = 1.0f / __fsqrt_rn(ux * ux + uy * uy + uz * uz + 1e-12f);
        ux *= rn; uy *= rn; uz *= rn;
        float bx = __fsub_rn(xp, x0), by = __fsub_rn(yp, y0), bz = __fsub_rn(zp, z0);
        float dnb = __fsqrt_rn(__fadd_rn(ssq3_exact(bx, by, bz), 1e-12f));
        float bb = (dnb > 3.6f && dnb < 4.0f) ? 1.0f : 0.0f;
        float vx = bx * bb, vy = by * bb, vz = bz * bb;
        rn = 1.0f / __fsqrt_rn(vx * vx + vy * vy + vz * vz + 1e-12f);
        vx *= rn; vy *= rn; vz *= rn;
        float ox = ux - vx, oy = uy - vy, oz = uz - vz;
        rn = 1.0f / __fsqrt_rn(ox * ox + oy * oy + oz * oz + 1e-12f);
        ox *= rn; oy *= rn; oz *= rn;
        float cx = uy * vz - uz * vy, cy = uz * vx - ux * vz, cz = ux * vy - uy * vx;
        rn = 1.0f / __fsqrt_rn(cx * cx + cy * cy + cz * cz + 1e-12f);
        cx *= rn; cy *= rn; cz *= rn;
        float rx = oy * cz - oz * cy, ry = oz * cx - ox * cz, rz = ox * cy - oy * cx;
        o[0] = ox; o[1] = oy; o[2] = oz;
        o[3] = cx; o[4] = cy; o[5] = cz;
        o[6] = rx; o[7] = ry; o[8] = rz;
    }
    float* dst = Onode + (size_t)idx * 9;
#pragma unroll
    for (int r = 0; r < 9; ++r) dst[r] = o[r];
}

// ---------- kernel B: top-K, one wave per row, 4 rows per block ----------
// State per lane: 3-deep cache (k1<k2<k3) of smallest unpopped keys. Pops happen
// in increasing key order, so popped keys of a lane == its keys <= last winner g.
// Cache-empty (3rd pop on one lane) is rare -> execz-skipped rebuild recomputes.
__global__ __launch_bounds__(256) void ktopk(const float* __restrict__ Ca,
                                             const float* __restrict__ mask,
                                             int* __restrict__ Eidx,
                                             float* __restrict__ Dn,
                                             float* __restrict__ outI) {
    const int row = blockIdx.x * 4 + (threadIdx.x >> 6);
    const int lane = threadIdx.x & 63;
    const int b = row / LQ, i = row - b * LQ;

    const float* Cb = Ca + (size_t)b * LQ * 3;
    const float* Mb = mask + (size_t)b * LQ;
    const float xi = Cb[i * 3 + 0], yi = Cb[i * 3 + 1], zi = Cb[i * 3 + 2];
    const float mi = Mb[i];

    // pass 1: Dmax (no stored arrays)
    float lmax = 0.0f;
#pragma unroll
    for (int s = 0; s < 24; ++s) {
        int j = lane + (s << 6);
        float dx = __fsub_rn(Cb[j * 3 + 0], xi);
        float dy = __fsub_rn(Cb[j * 3 + 1], yi);
        float dz = __fsub_rn(Cb[j * 3 + 2], zi);
        float m2 = __fmul_rn(mi, Mb[j]);
        float d = __fmul_rn(m2, __fsqrt_rn(__fadd_rn(ssq3_exact(dx, dy, dz), 1e-6f)));
        lmax = fmaxf(lmax, d);
    }
#pragma unroll
    for (int off = 1; off < 64; off <<= 1) lmax = fmaxf(lmax, __shfl_xor(lmax, off));
    const float Dmax = lmax;

    // pass 2: recompute keys, build top-3 cache in registers (no bound)
    unsigned long long k1 = ~0ull, k2 = ~0ull, k3 = ~0ull;
#pragma unroll
    for (int s = 0; s < 24; ++s) {
        int j = lane + (s << 6);
        float dx = __fsub_rn(Cb[j * 3 + 0], xi);
        float dy = __fsub_rn(Cb[j * 3 + 1], yi);
        float dz = __fsub_rn(Cb[j * 3 + 2], zi);
        float m2 = __fmul_rn(mi, Mb[j]);
        float d = __fmul_rn(m2, __fsqrt_rn(__fadd_rn(ssq3_exact(dx, dy, dz), 1e-6f)));
        float adj = __fadd_rn(d, __fmul_rn(__fsub_rn(1.0f, m2), Dmax));
        unsigned long long key = (((unsigned long long)__float_as_uint(adj)) << 32) | (unsigned)j;
        if (key < k1)      { k3 = k2; k2 = k1; k1 = key; }
        else if (key < k2) { k3 = k2; k2 = key; }
        else if (key < k3) { k3 = key; }
    }

    unsigned long long res = 0;
#pragma unroll 1
    for (int k = 0; k < KQ; ++k) {
        unsigned long long g = k1;
#pragma unroll
        for (int off = 1; off < 64; off <<= 1) {
            unsigned long long o = __shfl_xor(g, off);
            g = umin64(g, o);
        }
        if (lane == k) res = g;
        bool pop = (k1 == g);
        k1 = pop ? k2 : k1;
        k2 = pop ? k3 : k2;
        k3 = pop ? ~0ull : k3;
        if (__builtin_expect(pop & (k1 == ~0ull), 0)) {
            // cold rebuild: 3 smallest keys strictly greater than g
#pragma unroll 1
            for (int s = 0; s < 24; ++s) {
                int j = lane + (s << 6);
                float dx = __fsub_rn(Cb[j * 3 + 0], xi);
                float dy = __fsub_rn(Cb[j * 3 + 1], yi);
                float dz = __fsub_rn(Cb[j * 3 + 2], zi);
                float m2 = __fmul_rn(mi, Mb[j]);
                float d = __fmul_rn(m2, __fsqrt_rn(__fadd_rn(ssq3_exact(dx, dy, dz), 1e-6f)));
                float adj = __fadd_rn(d, __fmul_rn(__fsub_rn(1.0f, m2), Dmax));
                unsigned long long key = (((unsigned long long)__float_as_uint(adj)) << 32) | (unsigned)j;
                if (key > g) {
                    if (key < k1)      { k3 = k2; k2 = k1; k1 = key; }
                    else if (key < k2) { k3 = k2; k2 = key; }
                    else if (key < k3) { k3 = key; }
                }
            }
        }
    }

    if (lane < KQ) {
        unsigned j = (unsigned)(res & 0xffffffffu);
        Eidx[(size_t)row * KQ + lane] = (int)j;
        Dn[(size_t)row * KQ + lane] = __uint_as_float((unsigned)(res >> 32));
        outI[(size_t)row * KQ + lane] = (float)j;
    }
}

// ---------- kernel C: features (bf16) + MFMA GEMM + LayerNorm ----------
__global__ __launch_bounds__(256) void kfeat(const float* __restrict__ Ca,
                                             const int* __restrict__ ridx,
                                             const int* __restrict__ chl,
                                             const float* __restrict__ Wpos,
                                             const float* __restrict__ bpos,
                                             const float* __restrict__ gamma,
                                             const float* __restrict__ beta,
                                             const int* __restrict__ Eidx,
                                             const float* __restrict__ Dn,
                                             const float* __restrict__ Onode,
                                             const unsigned short* __restrict__ wpack,
                                             float* __restrict__ outE) {
    const int row = blockIdx.x;
    const int b = row / LQ, i = row - b * LQ;
    const int tid = threadIdx.x;

    __shared__ __align__(16) unsigned short Afrag[2 * 6 * 64 * 8];   // 6144 u16 = 12288 B
    __shared__ __align__(16) float Outb[KQ * 132];                   // 15840 B
    __shared__ float dists[KQ][9];
    __shared__ int sEidx[KQ];
    __shared__ float sDn[KQ];

    const float* Cb = Ca + (size_t)b * LQ * 3;

    // ---- phase 0: zero ALL of Afrag (6144 u16 = 768 uint4), load Eidx/Dn ----
    {
        uint4* az = (uint4*)Afrag;
        for (int t = tid; t < 768; t += 256) az[t] = make_uint4(0, 0, 0, 0);
        if (tid < KQ) {
            sEidx[tid] = Eidx[(size_t)row * KQ + tid];
            sDn[tid] = Dn[(size_t)row * KQ + tid];
        }
    }
    __syncthreads();

    unsigned int* Apair = (unsigned int*)Afrag;   // dword view for pair writes

    // ---- phase 1: dists (u<270), orientation (270..299), positional (300..539) ----
    for (int u = tid; u < 540; u += 256) {
        if (u < 270) {
            int e = u / 9, s = u - e * 9;
            if (s == 0) {
                dists[e][0] = sDn[e];
            } else {
                const int TA[9] = {0, -1, 1, -1, -1, 0, 0, 1, 1};
                const int TB[9] = {0, -1, 1,  0,  1, -1, 1, -1, 0};
                int j = sEidx[e];
                int ia = i + TA[s], jb = j + TB[s];
                float ax = 0.f, ay = 0.f, az = 0.f, bx = 0.f, by = 0.f, bz = 0.f;
                if (ia >= 0 && ia < LQ) { ax = Cb[ia * 3]; ay = Cb[ia * 3 + 1]; az = Cb[ia * 3 + 2]; }
                if (jb >= 0 && jb < LQ) { bx = Cb[jb * 3]; by = Cb[jb * 3 + 1]; bz = Cb[jb * 3 + 2]; }
                dists[e][s] = edist_exact(ax, ay, az, bx, by, bz);
            }
        } else if (u < 300) {
            int e = u - 270;
            int j = sEidx[e];
            float pic0 = Cb[i * 3], pic1 = Cb[i * 3 + 1], pic2 = Cb[i * 3 + 2];
            float pjc0 = Cb[j * 3], pjc1 = Cb[j * 3 + 1], pjc2 = Cb[j * 3 + 2];
            const float* Op = Onode + ((size_t)b * LQ + i) * 9;
            const float* Oq = Onode + ((size_t)b * LQ + j) * 9;
            float oi[9], oj[9];
#pragma unroll
            for (int r = 0; r < 9; ++r) { oi[r] = Op[r]; oj[r] = Oq[r]; }
            float dx = pjc0 - pic0, dy = pjc1 - pic1, dz = pjc2 - pic2;
            float v0 = oi[0] * dx + oi[1] * dy + oi[2] * dz;
            float v1 = oi[3] * dx + oi[4] * dy + oi[5] * dz;
            float v2 = oi[6] * dx + oi[7] * dy + oi[8] * dz;
            float rn = 1.0f / __fsqrt_rn(v0 * v0 + v1 * v1 + v2 * v2 + 1e-12f);
            v0 *= rn; v1 *= rn; v2 *= rn;
            float R[3][3];
#pragma unroll
            for (int ii = 0; ii < 3; ++ii)
#pragma unroll
                for (int mm = 0; mm < 3; ++mm)
                    R[ii][mm] = oi[ii] * oj[mm] + oi[3 + ii] * oj[3 + mm] + oi[6 + ii] * oj[6 + mm];
            float Rxx = R[0][0], Ryy = R[1][1], Rzz = R[2][2];
            float m0 = 0.5f * __fsqrt_rn(fabsf(1.0f + (Rxx - Ryy - Rzz)) + 1e-12f);
            float m1 = 0.5f * __fsqrt_rn(fabsf(1.0f + (-Rxx + Ryy - Rzz)) + 1e-12f);
            float m2 = 0.5f * __fsqrt_rn(fabsf(1.0f + (-Rxx - Ryy + Rzz)) + 1e-12f);
            float qx = sgnf(R[2][1] - R[1][2]) * m0;
            float qy = sgnf(R[0][2] - R[2][0]) * m1;
            float qz = sgnf(R[1][0] - R[0][1]) * m2;
            float qw = __fsqrt_rn(fmaxf(1.0f + (Rxx + Ryy + Rzz), 0.0f) + 1e-12f) * 0.5f;
            rn = 1.0f / __fsqrt_rn(qx * qx + qy * qy + qz * qz + qw * qw + 1e-12f);
            qx *= rn; qy *= rn; qz *= rn; qw *= rn;
            unsigned int p0 = (unsigned)f2bf(v0) | ((unsigned)f2bf(v1) << 16);
            unsigned int p1 = (unsigned)f2bf(v2) | ((unsigned)f2bf(qx) << 16);
            unsigned int p2 = (unsigned)f2bf(qy) | ((unsigned)f2bf(qz) << 16);
            unsigned int p3 = (unsigned)f2bf(qw);
            Apair[fragoff(e, 160) >> 1] = p0;
            Apair[fragoff(e, 162) >> 1] = p1;
            Apair[fragoff(e, 164) >> 1] = p2;
            Apair[fragoff(e, 166) >> 1] = p3;
        } else {
            int p = u - 300;                 // 240 jobs: e(30) x 8 pairs
            int e = p >> 3, pr = p & 7;
            int c = pr << 1;                 // 0..14
            int j = sEidx[e];
            int off = ridx[(size_t)b * LQ + i] - ridx[(size_t)b * LQ + j];
            int ech = (chl[(size_t)b * LQ + i] == chl[(size_t)b * LQ + j]);
            int dd = ech ? min(max(off + 32, 0), 64) : 65;
            float f0 = Wpos[c * POS_CLS + dd] + bpos[c];
            float f1 = Wpos[(c + 1) * POS_CLS + dd] + bpos[c + 1];
            Apair[fragoff(e, c) >> 1] = (unsigned)f2bf(f0) | ((unsigned)f2bf(f1) << 16);
        }
    }
    __syncthreads();

    // ---- phase 2: RBF features, written as bf16 pairs (30 x 72 pairs) ----
    for (int t = tid; t < KQ * 72; t += 256) {
        int e = t / 72, p = t - e * 72;
        int c = 16 + (p << 1);
        int s = (c - 16) >> 4, r = (c - 16) & 15;
        float d = dists[e][s];
        float z0 = (d - (2.0f + (float)r * 1.3333334f)) * 0.8f;
        float z1 = (d - (2.0f + (float)(r + 1) * 1.3333334f)) * 0.8f;
        float g0 = __expf(-(z0 * z0));
        float g1 = __expf(-(z1 * z1));
        Apair[fragoff(e, c) >> 1] = (unsigned)f2bf(g0) | ((unsigned)f2bf(g1) << 16);
    }
    __syncthreads();

    // ---- phase 3: MFMA GEMM: D[30x128] = A[32x192] * B[192x128] ----
    {
        const int l = tid & 63, w = tid >> 6;    // wave w owns f in [32w, 32w+32)
        const bf16x8* Af = (const bf16x8*)Afrag;
        const bf16x8* Bf = (const bf16x8*)wpack;
        f32x4 acc00 = {0.f, 0.f, 0.f, 0.f}, acc01 = acc00, acc10 = acc00, acc11 = acc00;
#pragma unroll
        for (int kk = 0; kk < 6; ++kk) {
            bf16x8 a0 = Af[kk * 64 + l];
            bf16x8 a1 = Af[(6 + kk) * 64 + l];
            bf16x8 b0 = Bf[(size_t)(kk * 8 + 2 * w) * 64 + l];
            bf16x8 b1 = Bf[(size_t)(kk * 8 + 2 * w + 1) * 64 + l];
            acc00 = __builtin_amdgcn_mfma_f32_16x16x32_bf16(a0, b0, acc00, 0, 0, 0);
            acc01 = __builtin_amdgcn_mfma_f32_16x16x32_bf16(a0, b1, acc01, 0, 0, 0);
            acc10 = __builtin_amdgcn_mfma_f32_16x16x32_bf16(a1, b0, acc10, 0, 0, 0);
            acc11 = __builtin_amdgcn_mfma_f32_16x16x32_bf16(a1, b1, acc11, 0, 0, 0);
        }
        // D layout: col = l&15, row = (l>>4)*4 + reg
        int colbase0 = (2 * w) * 16 + (l & 15);
        int colbase1 = (2 * w + 1) * 16 + (l & 15);
        int rbase = (l >> 4) * 4;
#pragma unroll
        for (int r = 0; r < 4; ++r) {
            int e0 = rbase + r;          // m=0 tile: rows 0..15 all valid
            Outb[e0 * 132 + colbase0] = acc00[r];
            Outb[e0 * 132 + colbase1] = acc01[r];
            int e1 = 16 + rbase + r;     // m=1 tile: rows 16..31, keep <30
            if (e1 < KQ) {
                Outb[e1 * 132 + colbase0] = acc10[r];
                Outb[e1 * 132 + colbase1] = acc11[r];
            }
        }
    }
    __syncthreads();

    // ---- phase 4: LayerNorm stats (8 threads per edge) ----
    __shared__ float smu[KQ], sinv[KQ];
    if (tid < KQ * 8) {
        int e = tid >> 3, g = tid & 7;
        float s1 = 0.f, s2 = 0.f;
#pragma unroll
        for (int q = 0; q < 16; ++q) {
            float v = Outb[e * 132 + g * 16 + q];
            s1 += v; s2 += v * v;
        }
#pragma unroll
        for (int off = 1; off < 8; off <<= 1) {
            s1 += __shfl_xor(s1, off);
            s2 += __shfl_xor(s2, off);
        }
        if (g == 0) {
            float mu = s1 * (1.0f / 128.0f);
            float var = s2 * (1.0f / 128.0f) - mu * mu;
            smu[e] = mu;
            sinv[e] = 1.0f / __fsqrt_rn(var + 1e-5f);
        }
    }
    __syncthreads();

    // ---- phase 5: normalize + f32 store (float4, coalesced) ----
    float* dst = outE + (size_t)row * (KQ * EDGE_F);
    for (int t = tid; t < KQ * EDGE_F / 4; t += 256) {
        int fi = t << 2;
        int e = fi >> 7, f0 = fi & 127;
        float4 x = *(const float4*)&Outb[e * 132 + f0];
        float4 gm = *(const float4*)&gamma[f0];
        float4 bt = *(const float4*)&beta[f0];
        float mu = smu[e], iv = sinv[e];
        float4 o;
        o.x = (x.x - mu) * iv * gm.x + bt.x;
        o.y = (x.y - mu) * iv * gm.y + bt.y;
        o.z = (x.z - mu) * iv * gm.z + bt.z;
        o.w = (x.w - mu) * iv * gm.w + bt.w;
        *(float4*)&dst[fi] = o;
    }
}

extern "C" void kernel_launch(void* const* d_in, const int* in_sizes, int n_in,
                              void* d_out, int out_size, void* d_ws, size_t ws_size,
                              hipStream_t stream) {
    const float* Ca    = (const float*)d_in[0];
    const float* mask  = (const float*)d_in[1];
    const int*   ridx  = (const int*)d_in[2];
    const int*   chl   = (const int*)d_in[3];
    const float* Wpos  = (const float*)d_in[4];
    const float* bpos  = (const float*)d_in[5];
    const float* Wedge = (const float*)d_in[6];
    const float* gamma = (const float*)d_in[7];
    const float* beta  = (const float*)d_in[8];

    float* outE = (float*)d_out;                                        // E: B*L*K*128 f32
    float* outI = outE + (size_t)BQ * LQ * KQ * EDGE_F;                 // E_idx: B*L*K (as f32)

    char* ws = (char*)d_ws;
    int*            Eidx  = (int*)(ws + 0);                                          // 737280 B
    float*          Dn    = (float*)(ws + (size_t)BQ * LQ * KQ * 4);                 // 737280 B
    float*          Onode = (float*)(ws + (size_t)BQ * LQ * KQ * 8);                 // 221184 B
    unsigned short* wpack = (unsigned short*)(ws + (size_t)BQ * LQ * KQ * 8 + (size_t)BQ * LQ * 9 * 4);  // 49152 B

    kprep<<<120, 256, 0, stream>>>(Wedge, wpack, Ca, Onode);
    ktopk<<<(BQ * LQ) / 4, 256, 0, stream>>>(Ca, mask, Eidx, Dn, outI);
    kfeat<<<BQ * LQ, 256, 0, stream>>>(Ca, ridx, chl, Wpos, bpos, gamma, beta,
                                       Eidx, Dn, Onode, wpack, outE);
}